// Round 3
// baseline (705.267 us; speedup 1.0000x reference)
//
#include <hip/hip_runtime.h>

#define NEG_SLOPE 0.2f
#define LN_EPS 1e-5f

__device__ __forceinline__ float wsum64(float v){
  #pragma unroll
  for (int o = 32; o >= 1; o >>= 1) v += __shfl_xor(v, o);
  return v;
}
__device__ __forceinline__ float rlF(float v, int lane){
  return __int_as_float(__builtin_amdgcn_readlane(__float_as_int(v), lane));
}
__device__ __forceinline__ int rlI(int v, int lane){
  return __builtin_amdgcn_readlane(v, lane);
}
// DPP add: v += dpp(v, ctrl), bound_ctrl -> 0-fill
#define DPPADD(v, C) { int _x = __builtin_amdgcn_update_dpp(0, __float_as_int(v), C, 0xF, 0xF, true); v += __int_as_float(_x); }
// sum over each 32-lane half (rows of 16 + bcast15), then select own half's sum
__device__ __forceinline__ float red32sel(float r, bool lowhalf){
  DPPADD(r, 0x111); // row_shr:1
  DPPADD(r, 0x112); // row_shr:2
  DPPADD(r, 0x114); // row_shr:4
  DPPADD(r, 0x118); // row_shr:8
  DPPADD(r, 0x142); // row_bcast15
  float lo = rlF(r, 31), hi = rlF(r, 63);
  return lowhalf ? lo : hi;
}
__device__ __forceinline__ float dot16(const float4 a0, const float4 a1,
                                       const float4 a2, const float4 a3,
                                       const float* w){
  float s = a0.x * w[0];
  s = fmaf(a0.y, w[1], s);  s = fmaf(a0.z, w[2], s);  s = fmaf(a0.w, w[3], s);
  s = fmaf(a1.x, w[4], s);  s = fmaf(a1.y, w[5], s);  s = fmaf(a1.z, w[6], s);
  s = fmaf(a1.w, w[7], s);  s = fmaf(a2.x, w[8], s);  s = fmaf(a2.y, w[9], s);
  s = fmaf(a2.z, w[10], s); s = fmaf(a2.w, w[11], s); s = fmaf(a3.x, w[12], s);
  s = fmaf(a3.y, w[13], s); s = fmaf(a3.z, w[14], s); s = fmaf(a3.w, w[15], s);
  return s;
}

// ---------------- CSR build ----------------
__global__ void k_count(const int* __restrict__ dst, int* __restrict__ deg, int E){
  int e = blockIdx.x * blockDim.x + threadIdx.x;
  if (e < E) atomicAdd(&deg[dst[e]], 1);
}

__global__ void k_scan_blk(const int* __restrict__ deg, int* __restrict__ part,
                           int* __restrict__ sums, int n){
  __shared__ int buf[256];
  int t = threadIdx.x, i = blockIdx.x * 256 + t;
  int v = (i < n) ? deg[i] : 0;
  buf[t] = v; __syncthreads();
  #pragma unroll
  for (int off = 1; off < 256; off <<= 1){
    int x = (t >= off) ? buf[t - off] : 0;
    __syncthreads(); buf[t] += x; __syncthreads();
  }
  if (i < n) part[i] = buf[t] - v;
  if (t == 255) sums[blockIdx.x] = buf[255];
}

__global__ void k_scan_top(int* __restrict__ sums, int nb){
  __shared__ int buf[256];
  int t = threadIdx.x;
  int v = (t < nb) ? sums[t] : 0;
  buf[t] = v; __syncthreads();
  #pragma unroll
  for (int off = 1; off < 256; off <<= 1){
    int x = (t >= off) ? buf[t - off] : 0;
    __syncthreads(); buf[t] += x; __syncthreads();
  }
  if (t < nb) sums[t] = buf[t] - v;
}

__global__ void k_scan_add(int* __restrict__ ptr, const int* __restrict__ sums,
                           int n, int Etot){
  int i = blockIdx.x * 256 + threadIdx.x;
  if (i < n) ptr[i] += sums[blockIdx.x];
  if (i == 0) ptr[n] = Etot;
}

__global__ void k_fill(const int* __restrict__ dst, const int* __restrict__ src,
                       int* __restrict__ cnt, const int* __restrict__ ptr,
                       int* __restrict__ eid, int* __restrict__ csrc, int E){
  int e = blockIdx.x * blockDim.x + threadIdx.x;
  if (e < E){
    int d = dst[e];
    int pos = atomicAdd(&cnt[d], 1);
    int p = ptr[d] + pos;
    eid[p] = e;
    csrc[p] = src[e];
  }
}

// loop_attr: wave per node, 4 edge-slots x 16 dims
__launch_bounds__(256)
__global__ void k_loop_attr(const float* __restrict__ eattr, const int* __restrict__ ptr,
                            const int* __restrict__ eid, float* __restrict__ lattr, int N){
  int node = blockIdx.x * 4 + (threadIdx.x >> 6);
  if (node >= N) return;
  int t = threadIdx.x & 63;
  int dim = t & 15, slot = t >> 4;
  int beg = ptr[node], end = ptr[node + 1];
  float s = 0.f;
  for (int i = beg + slot; i < end; i += 4){
    int e = eid[i];
    s += eattr[(size_t)e * 16 + dim];
  }
  s += __shfl_xor(s, 16);
  s += __shfl_xor(s, 32);
  if (slot == 0){
    float dg = (float)(end - beg);
    lattr[node * 16 + dim] = s / fmaxf(dg, 1.0f);
  }
}

// ---------------- Y[M,128] = X[M,128] @ W[128,128] + b ----------------
__launch_bounds__(256)
__global__ void k_gemm128(const float* __restrict__ X, const float* __restrict__ W,
                          const float* __restrict__ bias, float* __restrict__ Y, int M){
  __shared__ float Xs[64][129];
  int t = threadIdx.x;
  int rowBase = blockIdx.x * 64;
  int lr = t >> 5, lc = (t & 31) * 4;
  #pragma unroll
  for (int p = 0; p < 8; p++){
    int r = p * 8 + lr, gr = rowBase + r;
    float4 v = make_float4(0.f, 0.f, 0.f, 0.f);
    if (gr < M) v = *(const float4*)(X + (size_t)gr * 128 + lc);
    Xs[r][lc] = v.x; Xs[r][lc + 1] = v.y; Xs[r][lc + 2] = v.z; Xs[r][lc + 3] = v.w;
  }
  __syncthreads();
  int c0 = (t & 31) * 4, r0 = (t >> 5) * 8;
  float4 bv = *(const float4*)(bias + c0);
  float acc[8][4];
  #pragma unroll
  for (int i = 0; i < 8; i++){ acc[i][0] = bv.x; acc[i][1] = bv.y; acc[i][2] = bv.z; acc[i][3] = bv.w; }
  for (int k = 0; k < 128; k++){
    float4 wv = *(const float4*)(W + k * 128 + c0);
    #pragma unroll
    for (int i = 0; i < 8; i++){
      float x = Xs[r0 + i][k];
      acc[i][0] = fmaf(x, wv.x, acc[i][0]);
      acc[i][1] = fmaf(x, wv.y, acc[i][1]);
      acc[i][2] = fmaf(x, wv.z, acc[i][2]);
      acc[i][3] = fmaf(x, wv.w, acc[i][3]);
    }
  }
  #pragma unroll
  for (int i = 0; i < 8; i++){
    int gr = rowBase + r0 + i;
    if (gr < M){
      float4 o; o.x = acc[i][0]; o.y = acc[i][1]; o.z = acc[i][2]; o.w = acc[i][3];
      *(float4*)(Y + (size_t)gr * 128 + c0) = o;
    }
  }
}

__launch_bounds__(256)
__global__ void k_gemm_lr(const float* __restrict__ X,
                          const float* __restrict__ WL, const float* __restrict__ bL,
                          const float* __restrict__ WR, const float* __restrict__ bR,
                          float* __restrict__ YL, float* __restrict__ YR, int M){
  __shared__ float Xs[64][129];
  int t = threadIdx.x;
  int rowBase = blockIdx.x * 64;
  int lr = t >> 5, lc = (t & 31) * 4;
  #pragma unroll
  for (int p = 0; p < 8; p++){
    int r = p * 8 + lr, gr = rowBase + r;
    float4 v = make_float4(0.f, 0.f, 0.f, 0.f);
    if (gr < M) v = *(const float4*)(X + (size_t)gr * 128 + lc);
    Xs[r][lc] = v.x; Xs[r][lc + 1] = v.y; Xs[r][lc + 2] = v.z; Xs[r][lc + 3] = v.w;
  }
  __syncthreads();
  int c0 = (t & 31) * 4, r0 = (t >> 5) * 8;
  float4 bv = *(const float4*)(bL + c0);
  float4 cv = *(const float4*)(bR + c0);
  float aL[8][4], aR[8][4];
  #pragma unroll
  for (int i = 0; i < 8; i++){
    aL[i][0] = bv.x; aL[i][1] = bv.y; aL[i][2] = bv.z; aL[i][3] = bv.w;
    aR[i][0] = cv.x; aR[i][1] = cv.y; aR[i][2] = cv.z; aR[i][3] = cv.w;
  }
  for (int k = 0; k < 128; k++){
    float4 wl = *(const float4*)(WL + k * 128 + c0);
    float4 wr = *(const float4*)(WR + k * 128 + c0);
    #pragma unroll
    for (int i = 0; i < 8; i++){
      float x = Xs[r0 + i][k];
      aL[i][0] = fmaf(x, wl.x, aL[i][0]); aL[i][1] = fmaf(x, wl.y, aL[i][1]);
      aL[i][2] = fmaf(x, wl.z, aL[i][2]); aL[i][3] = fmaf(x, wl.w, aL[i][3]);
      aR[i][0] = fmaf(x, wr.x, aR[i][0]); aR[i][1] = fmaf(x, wr.y, aR[i][1]);
      aR[i][2] = fmaf(x, wr.z, aR[i][2]); aR[i][3] = fmaf(x, wr.w, aR[i][3]);
    }
  }
  #pragma unroll
  for (int i = 0; i < 8; i++){
    int gr = rowBase + r0 + i;
    if (gr < M){
      float4 o; o.x = aL[i][0]; o.y = aL[i][1]; o.z = aL[i][2]; o.w = aL[i][3];
      *(float4*)(YL + (size_t)gr * 128 + c0) = o;
      float4 q; q.x = aR[i][0]; q.y = aR[i][1]; q.z = aR[i][2]; q.w = aR[i][3];
      *(float4*)(YR + (size_t)gr * 128 + c0) = q;
    }
  }
}

// ---------------- GAT layer ----------------
// wave handles 4 consecutive nodes; edges for those nodes are contiguous in CSR.
// eattr staged lane-distributed per 64-edge chunk; per-edge broadcast via v_readlane.
// logit reduction via DPP row ops (VALU), xl gather distance-2 prefetched.
__launch_bounds__(256)
__global__ void k_gat(const float* __restrict__ xl, const float* __restrict__ xr,
                      const float* __restrict__ eattr, const float* __restrict__ lattr,
                      const int* __restrict__ csrc, const int* __restrict__ ptr,
                      const int* __restrict__ eid,
                      const float* __restrict__ We, const float* __restrict__ att,
                      const float* __restrict__ cb, float* __restrict__ hout, int N){
  const int t = threadIdx.x & 63;
  const int wv = threadIdx.x >> 6;
  const int node0 = (blockIdx.x * 4 + wv) * 4;
  if (node0 >= N) return;
  const bool lowhalf = (t < 32);

  float we0[16], we1[16];
  #pragma unroll
  for (int k = 0; k < 16; k++){ we0[k] = We[k * 128 + t]; we1[k] = We[k * 128 + 64 + t]; }
  const float att0 = att[t], att1 = att[64 + t];
  const float cb0 = cb[t],  cb1 = cb[64 + t];

  int pv[5];
  #pragma unroll
  for (int j = 0; j < 5; j++){
    int nn = node0 + j; nn = nn > N ? N : nn;
    pv[j] = __builtin_amdgcn_readfirstlane(ptr[nn]);
  }
  const int begAll = pv[0], endAll = pv[4];

  float xr0 = 0.f, xr1 = 0.f, mx0 = 0.f, mx1 = 0.f;
  float den0 = 1.f, den1 = 1.f, acc0 = 0.f, acc1 = 0.f;
  int jcur = 0;

  auto initNode = [&](int j2){
    int nd = node0 + j2;
    int ndc = nd < N ? nd : 0;
    const float4* lap = (const float4*)(lattr + (size_t)ndc * 16);
    float4 la0 = lap[0], la1 = lap[1], la2 = lap[2], la3 = lap[3];
    xr0 = xr[(size_t)ndc * 128 + t]; xr1 = xr[(size_t)ndc * 128 + 64 + t];
    float xs0 = xl[(size_t)ndc * 128 + t], xs1 = xl[(size_t)ndc * 128 + 64 + t];
    float m0 = xs0 + xr0 + dot16(la0, la1, la2, la3, we0);
    float m1 = xs1 + xr1 + dot16(la0, la1, la2, la3, we1);
    m0 = m0 > 0.f ? m0 : NEG_SLOPE * m0;
    m1 = m1 > 0.f ? m1 : NEG_SLOPE * m1;
    mx0 = red32sel(m0 * att0, lowhalf);
    mx1 = red32sel(m1 * att1, lowhalf);
    den0 = 1.f; den1 = 1.f; acc0 = xs0; acc1 = xs1;
  };
  auto finNode = [&](int j2){
    int nd = node0 + j2;
    if (nd < N){
      float o0 = acc0 / den0 + cb0; o0 = o0 > 0.f ? o0 : expm1f(o0);
      float o1 = acc1 / den1 + cb1; o1 = o1 > 0.f ? o1 : expm1f(o1);
      hout[(size_t)nd * 128 + t] = o0;
      hout[(size_t)nd * 128 + 64 + t] = o1;
    }
  };
  auto advance = [&](int nxt){
    while (jcur < 4 && nxt == pv[jcur + 1]){
      finNode(jcur); jcur++;
      if (jcur < 4) initNode(jcur);
    }
  };

  initNode(0);
  advance(begAll);

  float eaR[16];
  int slv = 0;

  for (int cbase = begAll; cbase < endAll; cbase += 64){
    // stage chunk: lane t owns edge cbase+t
    {
      int idx = cbase + t;
      bool va = idx < endAll;
      int e = va ? eid[idx] : 0;
      slv = va ? csrc[idx] : 0;
      const float4* ep = (const float4*)(eattr + (size_t)e * 16);
      float4 A0 = ep[0], A1 = ep[1], A2 = ep[2], A3 = ep[3];
      eaR[0]=A0.x; eaR[1]=A0.y; eaR[2]=A0.z; eaR[3]=A0.w;
      eaR[4]=A1.x; eaR[5]=A1.y; eaR[6]=A1.z; eaR[7]=A1.w;
      eaR[8]=A2.x; eaR[9]=A2.y; eaR[10]=A2.z; eaR[11]=A2.w;
      eaR[12]=A3.x; eaR[13]=A3.y; eaR[14]=A3.z; eaR[15]=A3.w;
    }
    int cnt = endAll - cbase; cnt = cnt > 64 ? 64 : cnt;

    auto proc = [&](int ii, float xa, float xb){
      float b0  = rlF(eaR[0],  ii), b1  = rlF(eaR[1],  ii), b2  = rlF(eaR[2],  ii), b3  = rlF(eaR[3],  ii);
      float b4  = rlF(eaR[4],  ii), b5  = rlF(eaR[5],  ii), b6  = rlF(eaR[6],  ii), b7  = rlF(eaR[7],  ii);
      float b8  = rlF(eaR[8],  ii), b9  = rlF(eaR[9],  ii), b10 = rlF(eaR[10], ii), b11 = rlF(eaR[11], ii);
      float b12 = rlF(eaR[12], ii), b13 = rlF(eaR[13], ii), b14 = rlF(eaR[14], ii), b15 = rlF(eaR[15], ii);
      float e0 = b0 * we0[0], e1 = b0 * we1[0];
      e0 = fmaf(b1, we0[1], e0);   e1 = fmaf(b1, we1[1], e1);
      e0 = fmaf(b2, we0[2], e0);   e1 = fmaf(b2, we1[2], e1);
      e0 = fmaf(b3, we0[3], e0);   e1 = fmaf(b3, we1[3], e1);
      e0 = fmaf(b4, we0[4], e0);   e1 = fmaf(b4, we1[4], e1);
      e0 = fmaf(b5, we0[5], e0);   e1 = fmaf(b5, we1[5], e1);
      e0 = fmaf(b6, we0[6], e0);   e1 = fmaf(b6, we1[6], e1);
      e0 = fmaf(b7, we0[7], e0);   e1 = fmaf(b7, we1[7], e1);
      e0 = fmaf(b8, we0[8], e0);   e1 = fmaf(b8, we1[8], e1);
      e0 = fmaf(b9, we0[9], e0);   e1 = fmaf(b9, we1[9], e1);
      e0 = fmaf(b10, we0[10], e0); e1 = fmaf(b10, we1[10], e1);
      e0 = fmaf(b11, we0[11], e0); e1 = fmaf(b11, we1[11], e1);
      e0 = fmaf(b12, we0[12], e0); e1 = fmaf(b12, we1[12], e1);
      e0 = fmaf(b13, we0[13], e0); e1 = fmaf(b13, we1[13], e1);
      e0 = fmaf(b14, we0[14], e0); e1 = fmaf(b14, we1[14], e1);
      e0 = fmaf(b15, we0[15], e0); e1 = fmaf(b15, we1[15], e1);
      float m0 = xa + xr0 + e0; m0 = m0 > 0.f ? m0 : NEG_SLOPE * m0;
      float m1 = xb + xr1 + e1; m1 = m1 > 0.f ? m1 : NEG_SLOPE * m1;
      float l0 = red32sel(m0 * att0, lowhalf);
      float l1 = red32sel(m1 * att1, lowhalf);
      float nm0 = fmaxf(mx0, l0), nm1 = fmaxf(mx1, l1);
      float sc0 = __expf(mx0 - nm0), p0 = __expf(l0 - nm0);
      float sc1 = __expf(mx1 - nm1), p1 = __expf(l1 - nm1);
      den0 = fmaf(den0, sc0, p0); acc0 = fmaf(acc0, sc0, p0 * xa); mx0 = nm0;
      den1 = fmaf(den1, sc1, p1); acc1 = fmaf(acc1, sc1, p1 * xb); mx1 = nm1;
    };

    // distance-2 pipelined xl gather (src ids in registers)
    int sA = rlI(slv, 0);
    float pa0 = xl[(size_t)sA * 128 + t], pb0 = xl[(size_t)sA * 128 + 64 + t];
    float pa1 = 0.f, pb1 = 0.f;
    if (cnt > 1){
      int sB = rlI(slv, 1);
      pa1 = xl[(size_t)sB * 128 + t]; pb1 = xl[(size_t)sB * 128 + 64 + t];
    }
    int ii = 0;
    while (ii < cnt){
      {
        float xa = pa0, xb = pb0;
        if (ii + 2 < cnt){
          int sN = rlI(slv, ii + 2);
          pa0 = xl[(size_t)sN * 128 + t]; pb0 = xl[(size_t)sN * 128 + 64 + t];
        }
        proc(ii, xa, xb);
        advance(cbase + ii + 1);
      }
      ii++;
      if (ii >= cnt) break;
      {
        float xa = pa1, xb = pb1;
        if (ii + 2 < cnt){
          int sN = rlI(slv, ii + 2);
          pa1 = xl[(size_t)sN * 128 + t]; pb1 = xl[(size_t)sN * 128 + 64 + t];
        }
        proc(ii, xa, xb);
        advance(cbase + ii + 1);
      }
      ii++;
    }
  }
}

// ---------------- LayerNorm + ReLU-MLP head ----------------
__launch_bounds__(256)
__global__ void k_head(const float* __restrict__ h, const float* __restrict__ g,
                       const float* __restrict__ b, const float* __restrict__ w1,
                       const float* __restrict__ b1, const float* __restrict__ w2,
                       const float* __restrict__ b2, float* __restrict__ out, int N){
  __shared__ float sn[4][128];
  const int t = threadIdx.x & 63, wv = threadIdx.x >> 6;
  const int node = blockIdx.x * 4 + wv;
  float h0 = 0.f, h1 = 0.f;
  if (node < N){ h0 = h[(size_t)node * 128 + t]; h1 = h[(size_t)node * 128 + 64 + t]; }
  float mu = wsum64(h0 + h1) * (1.f / 128.f);
  float d0 = h0 - mu, d1 = h1 - mu;
  float var = wsum64(d0 * d0 + d1 * d1) * (1.f / 128.f);
  float rstd = rsqrtf(var + LN_EPS);
  sn[wv][t]      = d0 * rstd * g[t]      + b[t];
  sn[wv][t + 64] = d1 * rstd * g[t + 64] + b[t + 64];
  __syncthreads();
  float a = b1[t];
  #pragma unroll
  for (int k4 = 0; k4 < 32; k4++){
    float4 v = *(const float4*)&sn[wv][k4 * 4];
    a = fmaf(v.x, w1[(k4 * 4 + 0) * 64 + t], a);
    a = fmaf(v.y, w1[(k4 * 4 + 1) * 64 + t], a);
    a = fmaf(v.z, w1[(k4 * 4 + 2) * 64 + t], a);
    a = fmaf(v.w, w1[(k4 * 4 + 3) * 64 + t], a);
  }
  a = fmaxf(a, 0.f);
  float p0 = a * w2[t * 3 + 0], p1 = a * w2[t * 3 + 1], p2 = a * w2[t * 3 + 2];
  p0 = wsum64(p0); p1 = wsum64(p1); p2 = wsum64(p2);
  if (node < N && t == 0){
    out[(size_t)node * 3 + 0] = p0 + b2[0];
    out[(size_t)node * 3 + 1] = p1 + b2[1];
    out[(size_t)node * 3 + 2] = p2 + b2[2];
  }
}

extern "C" void kernel_launch(void* const* d_in, const int* in_sizes, int n_in,
                              void* d_out, int out_size, void* d_ws, size_t ws_size,
                              hipStream_t stream){
  const float* x    = (const float*)d_in[0];
  const int*   ei   = (const int*)d_in[1];
  const float* ea   = (const float*)d_in[2];
  const float* in_w = (const float*)d_in[3];
  const float* in_b = (const float*)d_in[4];
  const float* Wl   = (const float*)d_in[5];
  const float* bl   = (const float*)d_in[6];
  const float* Wr   = (const float*)d_in[7];
  const float* br   = (const float*)d_in[8];
  const float* We   = (const float*)d_in[9];
  const float* att  = (const float*)d_in[10];
  const float* cb   = (const float*)d_in[11];
  const float* lng  = (const float*)d_in[12];
  const float* lnb  = (const float*)d_in[13];
  const float* h1w  = (const float*)d_in[14];
  const float* h1b  = (const float*)d_in[15];
  const float* h2w  = (const float*)d_in[16];
  const float* h2b  = (const float*)d_in[17];
  float* out = (float*)d_out;

  int N = in_sizes[0] / 128;
  int E = in_sizes[1] / 2;
  const int* src = ei;
  const int* dst = ei + E;

  char* w = (char*)d_ws;
  size_t off = 0;
  auto alloc = [&](size_t bytes) -> char* {
    char* p = w + off;
    off = (off + bytes + 255) & ~(size_t)255;
    return p;
  };
  int*   deg   = (int*)alloc((size_t)N * 4);
  int*   cnt   = (int*)alloc((size_t)N * 4);
  int*   ptr   = (int*)alloc((size_t)(N + 1) * 4);
  int*   eid   = (int*)alloc((size_t)E * 4);
  int*   csrc  = (int*)alloc((size_t)E * 4);
  int*   bsum  = (int*)alloc(256 * 4);
  float* lattr = (float*)alloc((size_t)N * 16 * 4);
  float* h     = (float*)alloc((size_t)N * 128 * 4);
  float* xlb   = (float*)alloc((size_t)N * 128 * 4);
  float* xrb   = (float*)alloc((size_t)N * 128 * 4);

  int nb = (N + 255) / 256;
  hipMemsetAsync(deg, 0, (size_t)N * 4, stream);
  hipMemsetAsync(cnt, 0, (size_t)N * 4, stream);
  k_count<<<(E + 255) / 256, 256, 0, stream>>>(dst, deg, E);
  k_scan_blk<<<nb, 256, 0, stream>>>(deg, ptr, bsum, N);
  k_scan_top<<<1, 256, 0, stream>>>(bsum, nb);
  k_scan_add<<<nb, 256, 0, stream>>>(ptr, bsum, N, E);
  k_fill<<<(E + 255) / 256, 256, 0, stream>>>(dst, src, cnt, ptr, eid, csrc, E);
  k_loop_attr<<<(N + 3) / 4, 256, 0, stream>>>(ea, ptr, eid, lattr, N);

  k_gemm128<<<(N + 63) / 64, 256, 0, stream>>>(x, in_w, in_b, h, N);
  for (int l = 0; l < 2; l++){
    k_gemm_lr<<<(N + 63) / 64, 256, 0, stream>>>(h, Wl + l * 16384, bl + l * 128,
                                                 Wr + l * 16384, br + l * 128, xlb, xrb, N);
    k_gat<<<(N + 15) / 16, 256, 0, stream>>>(xlb, xrb, ea, lattr, csrc, ptr, eid,
                                             We + l * 2048, att + l * 128, cb + l * 128, h, N);
  }
  k_head<<<(N + 3) / 4, 256, 0, stream>>>(h, lng, lnb, h1w, h1b, h2w, h2b, out, N);
}